// Round 4
// baseline (264.483 us; speedup 1.0000x reference)
//
#include <hip/hip_runtime.h>
#include <hip/hip_fp16.h>

#define HEADS 4
#define DH    32
#define HW    4096
#define CIN   256
#define HID   128
#define KSPLIT 2
#define KHALF (HW / KSPLIT)
#define NIT   (KHALF / 64)

using half8   = __attribute__((ext_vector_type(8))) _Float16;
using half4   = __attribute__((ext_vector_type(4))) _Float16;
using half2v  = __attribute__((ext_vector_type(2))) _Float16;
using floatx4 = __attribute__((ext_vector_type(4))) float;

// P = exp2(s_log2 - 3*log2e); log2(e) folded into Q pre-scale, shift folded
// into the S-MFMA C-initializer. Fixed shift (no running max) => split-K
// partials combine by pure addition.
#define SHIFT2 4.328085122666891f
#define WQSCALE 0.25508275947f   // 32^-0.5 * log2(e)

// packed f32x2 -> f16x2 (cvt_pkrtz returns __fp16 vec; bit-cast to _Float16 vec)
static __device__ __forceinline__ half2v pk2(float a, float b) {
  return __builtin_bit_cast(half2v, __builtin_amdgcn_cvt_pkrtz(a, b));
}

// ---------------------------------------------------------------------------
// qkv_fused: QKV[o][b,p] = (w_qkv f32->f16, Q rows pre-scaled) @ x^T.
// x transposed through fp32 t[64][65] LDS tile, K in 4 quarters of 64.
// grid (6 m-tiles, 256 n-tiles) x 256
// ---------------------------------------------------------------------------
__global__ __launch_bounds__(256) void qkv_fused(
    const float* __restrict__ w, const float* __restrict__ x,
    _Float16* __restrict__ Qw, _Float16* __restrict__ Kw,
    _Float16* __restrict__ Vtw)
{
  __shared__ float t[64][65];
  __shared__ _Float16 As[64][72];
  __shared__ _Float16 Bs[64][72];
  const int mt = blockIdx.x, nt = blockIdx.y;
  const int b = nt >> 6, p0 = (nt & 63) * 64;
  const int tid = threadIdx.x;
  const int wv = tid >> 6, lane = tid & 63, lm = lane & 15, quad = lane >> 4;
  const float wscale = (mt < 2) ? WQSCALE : 1.0f;

  const float* Ag = w + (size_t)(mt * 64) * CIN;
  const float* xb = x + (size_t)b * CIN * HW + p0;

  floatx4 acc[4] = {{0,0,0,0},{0,0,0,0},{0,0,0,0},{0,0,0,0}};

  for (int kq = 0; kq < 4; ++kq) {
    __syncthreads();
    #pragma unroll
    for (int i = 0; i < 4; ++i) {
      int ci = tid + i * 256;
      int cc = ci >> 4, p4 = (ci & 15) * 4;
      *(float4*)&t[cc][p4] =
          *(const float4*)(xb + (size_t)(kq * 64 + cc) * HW + p4);
    }
    #pragma unroll
    for (int i = 0; i < 2; ++i) {
      int ci = tid + i * 256;
      int r = ci >> 3, c8 = (ci & 7) * 8;
      const float* src = Ag + (size_t)r * CIN + kq * 64 + c8;
      float4 u0 = *(const float4*)(src);
      float4 u1 = *(const float4*)(src + 4);
      half8 h = {(_Float16)(u0.x * wscale), (_Float16)(u0.y * wscale),
                 (_Float16)(u0.z * wscale), (_Float16)(u0.w * wscale),
                 (_Float16)(u1.x * wscale), (_Float16)(u1.y * wscale),
                 (_Float16)(u1.z * wscale), (_Float16)(u1.w * wscale)};
      *(half8*)&As[r][c8] = h;
    }
    __syncthreads();
    #pragma unroll
    for (int i = 0; i < 2; ++i) {
      int idx = tid + i * 256;
      int p = idx >> 3, c0 = (idx & 7) * 8;
      half8 v;
      #pragma unroll
      for (int k = 0; k < 8; ++k) v[k] = (_Float16)t[c0 + k][p];
      *(half8*)&Bs[p][c0] = v;
    }
    __syncthreads();
    #pragma unroll
    for (int ks = 0; ks < 2; ++ks) {
      half8 a = *(const half8*)&As[wv * 16 + lm][ks * 32 + quad * 8];
      #pragma unroll
      for (int ns = 0; ns < 4; ++ns) {
        half8 bf = *(const half8*)&Bs[ns * 16 + lm][ks * 32 + quad * 8];
        acc[ns] = __builtin_amdgcn_mfma_f32_16x16x32_f16(a, bf, acc[ns], 0, 0, 0);
      }
    }
  }

  const int sec = mt >> 1;                    // 0=Q 1=K 2=V
  const int o_base = (mt & 1) * 64 + wv * 16 + quad * 4;
  const int hh = o_base >> 5, dd = o_base & 31;
  const int bh = b * HEADS + hh;
  if (sec < 2) {
    _Float16* dst = (sec == 0) ? Qw : Kw;
    #pragma unroll
    for (int ns = 0; ns < 4; ++ns) {
      int p = p0 + ns * 16 + lm;
      half4 v = {(_Float16)acc[ns][0], (_Float16)acc[ns][1],
                 (_Float16)acc[ns][2], (_Float16)acc[ns][3]};
      *(half4*)(dst + ((size_t)bh * HW + p) * DH + dd) = v;
    }
  } else {
    #pragma unroll
    for (int ns = 0; ns < 4; ++ns) {
      int p = p0 + ns * 16 + lm;
      #pragma unroll
      for (int r = 0; r < 4; ++r)
        Vtw[((size_t)bh * DH + dd + r) * HW + p] = (_Float16)acc[ns][r];
    }
  }
}

// ---------------------------------------------------------------------------
// attn: register-dataflow flash attention, 2 q-tiles per wave, split-K x2.
// THIS ROUND: NO LDS AT ALL. R2/R3 showed adding resident waves buys nothing
// (69.7 -> 70.5 us): the LDS-staging + barrier-lockstep structure itself is
// the tax (VALUBusy+MfmaUtil ~= 102% of issue; 7.37M bank-conflict cycles).
// K/V per (bh,z) is 256 KB = L2-resident, and the MFMA fragment layouts are
// per-lane contiguous in global memory (K-frag: 16B at row f*16+lm; V-frag:
// 8B). So each wave loads fragments straight from global (L1/L2-served),
// register-double-buffered one iteration ahead. No barriers; waves free-run.
// XCD-locality swizzle: flat grid 1024, id&7 = XCD slot under round-robin
// dispatch -> each XCD serves 4 (bh,z) combos = 1 MB working set < 4 MB L2.
// ---------------------------------------------------------------------------
__global__ __launch_bounds__(256) void attn(
    const _Float16* __restrict__ Qw, const _Float16* __restrict__ Kw,
    const _Float16* __restrict__ Vtw, float* __restrict__ Op,
    float* __restrict__ lp)
{
  // decode swizzled flat id: xcd slot -> 4 combos of (bh,z), 32 qt each
  const int id = blockIdx.x;
  const int combo = (id & 7) * 4 + ((id >> 3) >> 5);
  const int qt = (id >> 3) & 31;
  const int bh = combo >> 1, z = combo & 1;

  const int tid = threadIdx.x;
  const int wv = tid >> 6, lane = tid & 63, lm = lane & 15, quad = lane >> 4;

  const _Float16* qbase =
      Qw + ((size_t)bh * HW + qt * 128 + wv * 16 + lm) * DH + quad * 8;
  const half8 qa0 = *(const half8*)qbase;
  const half8 qa1 = *(const half8*)(qbase + (size_t)64 * DH);

  const _Float16 one = (_Float16)1.0f;
  const half4 ones4 = {one, one, one, one};
  const floatx4 shiftc = {-SHIFT2, -SHIFT2, -SHIFT2, -SHIFT2};

  floatx4 oT[2][2] = {{{0,0,0,0},{0,0,0,0}},{{0,0,0,0},{0,0,0,0}}};
  floatx4 l4[2]    = {{0,0,0,0},{0,0,0,0}};

  // per-lane fragment base pointers into this block's K-range
  const _Float16* kp  = Kw  + (size_t)bh * HW * DH + (size_t)z * KHALF * DH
                        + (size_t)lm * DH + quad * 8;
  const _Float16* vp0 = Vtw + (size_t)bh * DH * HW + (size_t)z * KHALF
                        + (size_t)lm * HW + quad * 4;
  const _Float16* vp1 = vp0 + (size_t)16 * HW;

  half8 kf0[4], kf1[4];
  half4 vf0[4][2], vf1[4][2];

#define LOADKV(KF, VF, itv)                                                  \
  {                                                                          \
    const _Float16* kp_  = kp  + (size_t)(itv) * 64 * DH;                    \
    const _Float16* vp0_ = vp0 + (size_t)(itv) * 64;                         \
    const _Float16* vp1_ = vp1 + (size_t)(itv) * 64;                         \
    KF[0] = *(const half8*)(kp_);                                            \
    KF[1] = *(const half8*)(kp_ + 16 * DH);                                  \
    KF[2] = *(const half8*)(kp_ + 32 * DH);                                  \
    KF[3] = *(const half8*)(kp_ + 48 * DH);                                  \
    VF[0][0] = *(const half4*)(vp0_);                                        \
    VF[0][1] = *(const half4*)(vp1_);                                        \
    VF[1][0] = *(const half4*)(vp0_ + 16);                                   \
    VF[1][1] = *(const half4*)(vp1_ + 16);                                   \
    VF[2][0] = *(const half4*)(vp0_ + 32);                                   \
    VF[2][1] = *(const half4*)(vp1_ + 32);                                   \
    VF[3][0] = *(const half4*)(vp0_ + 48);                                   \
    VF[3][1] = *(const half4*)(vp1_ + 48);                                   \
  }

#define COMPUTE(KF, VF)                                                      \
  {                                                                          \
    _Pragma("unroll")                                                        \
    for (int f = 0; f < 4; ++f) {                                            \
      floatx4 sT0 = __builtin_amdgcn_mfma_f32_16x16x32_f16(KF[f], qa0, shiftc, 0, 0, 0); \
      floatx4 sT1 = __builtin_amdgcn_mfma_f32_16x16x32_f16(KF[f], qa1, shiftc, 0, 0, 0); \
      half2v a0 = pk2(__builtin_amdgcn_exp2f(sT0[0]), __builtin_amdgcn_exp2f(sT0[1])); \
      half2v b0 = pk2(__builtin_amdgcn_exp2f(sT0[2]), __builtin_amdgcn_exp2f(sT0[3])); \
      half2v a1 = pk2(__builtin_amdgcn_exp2f(sT1[0]), __builtin_amdgcn_exp2f(sT1[1])); \
      half2v b1 = pk2(__builtin_amdgcn_exp2f(sT1[2]), __builtin_amdgcn_exp2f(sT1[3])); \
      half4 pb0 = {a0.x, a0.y, b0.x, b0.y};                                  \
      half4 pb1 = {a1.x, a1.y, b1.x, b1.y};                                  \
      l4[0] = __builtin_amdgcn_mfma_f32_16x16x16f16(ones4, pb0, l4[0], 0, 0, 0); \
      l4[1] = __builtin_amdgcn_mfma_f32_16x16x16f16(ones4, pb1, l4[1], 0, 0, 0); \
      _Pragma("unroll")                                                      \
      for (int g = 0; g < 2; ++g) {                                          \
        oT[0][g] = __builtin_amdgcn_mfma_f32_16x16x16f16(VF[f][g], pb0, oT[0][g], 0, 0, 0); \
        oT[1][g] = __builtin_amdgcn_mfma_f32_16x16x16f16(VF[f][g], pb1, oT[1][g], 0, 0, 0); \
      }                                                                      \
    }                                                                        \
  }

  LOADKV(kf0, vf0, 0);
  for (int it = 0; it < NIT; it += 2) {
    LOADKV(kf1, vf1, it + 1);
    COMPUTE(kf0, vf0);
    const int i2 = (it + 2 < NIT) ? it + 2 : NIT - 1;  // clamp (extra load unused)
    LOADKV(kf0, vf0, i2);
    COMPUTE(kf1, vf1);
  }
#undef LOADKV
#undef COMPUTE

  // epilogue: UNNORMALIZED f32 partial stores -> Op[z][b][p][hid], plus
  // row-sum partials lp[z][bh][p] (l4[t][0] replicated across quad/r).
  const int b = bh >> 2, hh = bh & 3;
  #pragma unroll
  for (int t = 0; t < 2; ++t) {
    const int row = qt * 128 + t * 64 + wv * 16 + lm;
    float* obase = Op +
        ((size_t)z * 4 * HW + (size_t)b * HW + row) * HID + hh * DH;
    #pragma unroll
    for (int g = 0; g < 2; ++g) {
      float4 v = {oT[t][g][0], oT[t][g][1], oT[t][g][2], oT[t][g][3]};
      *(float4*)(obase + g * 16 + quad * 4) = v;
    }
    if (quad == 0)
      lp[(size_t)z * HEADS * 4 * HW + (size_t)bh * HW + row] = l4[t][0];
  }
}

// ---------------------------------------------------------------------------
// out_gemm: out[o][b,p] = w_out(256x128, cvt inline) @ Ot^T + bias.
// Split-K combine folded into B-staging — reads the two f32 O-partials,
// adds, normalizes by 1/(l0+l1) (per row & head), cvt to f16.
// Tile 64x64, K=128. grid (4 m-tiles, 256 n-tiles) x 256.
// ---------------------------------------------------------------------------
__global__ __launch_bounds__(256) void out_gemm(
    const float* __restrict__ wo, const float* __restrict__ Op,
    const float* __restrict__ lp, const float* __restrict__ bo,
    float* __restrict__ out)
{
  __shared__ _Float16 As[64][136];
  __shared__ _Float16 Bs[64][136];
  __shared__ float os[64][68];
  __shared__ float inv_l[64][4];
  const int mt = blockIdx.x, nt = blockIdx.y;
  const int b = nt >> 6, p0 = (nt & 63) * 64;
  const int tid = threadIdx.x;
  const int wv = tid >> 6, lane = tid & 63, lm = lane & 15, quad = lane >> 4;

  // combine row sums: inv_l[p][head] = 1/(l_z0 + l_z1)
  {
    const int p = tid >> 2, hh = tid & 3;
    const size_t qi = (size_t)(b * HEADS + hh) * HW + p0 + p;
    inv_l[p][hh] = 1.0f / (lp[qi] + lp[(size_t)HEADS * 4 * HW + qi]);
  }
  __syncthreads();

  const float* Ag  = wo + (size_t)(mt * 64) * HID;
  const float* Bp0 = Op + ((size_t)b * HW + p0) * HID;          // z = 0
  const float* Bp1 = Bp0 + (size_t)4 * HW * HID;                // z = 1

  #pragma unroll
  for (int i = 0; i < 4; ++i) {
    int ci = tid + i * 256;
    int r = ci >> 4, c8 = (ci & 15) * 8;
    const float* src = Ag + (size_t)r * HID + c8;
    float4 u0 = *(const float4*)(src);
    float4 u1 = *(const float4*)(src + 4);
    half8 h = {(_Float16)u0.x, (_Float16)u0.y, (_Float16)u0.z, (_Float16)u0.w,
               (_Float16)u1.x, (_Float16)u1.y, (_Float16)u1.z, (_Float16)u1.w};
    *(half8*)&As[r][c8] = h;

    const float* s0 = Bp0 + (size_t)r * HID + c8;
    const float* s1 = Bp1 + (size_t)r * HID + c8;
    float4 o0 = *(const float4*)(s0);
    float4 o1 = *(const float4*)(s0 + 4);
    float4 o2 = *(const float4*)(s1);
    float4 o3 = *(const float4*)(s1 + 4);
    const float sc = inv_l[r][c8 >> 5];   // 8 cols stay within one head
    half8 hb = {(_Float16)((o0.x + o2.x) * sc), (_Float16)((o0.y + o2.y) * sc),
                (_Float16)((o0.z + o2.z) * sc), (_Float16)((o0.w + o2.w) * sc),
                (_Float16)((o1.x + o3.x) * sc), (_Float16)((o1.y + o3.y) * sc),
                (_Float16)((o1.z + o3.z) * sc), (_Float16)((o1.w + o3.w) * sc)};
    *(half8*)&Bs[r][c8] = hb;
  }
  __syncthreads();

  floatx4 acc[4] = {{0,0,0,0},{0,0,0,0},{0,0,0,0},{0,0,0,0}};
  #pragma unroll
  for (int ks = 0; ks < 4; ++ks) {
    half8 a = *(const half8*)&As[wv * 16 + lm][ks * 32 + quad * 8];
    #pragma unroll
    for (int ns = 0; ns < 4; ++ns) {
      half8 bf = *(const half8*)&Bs[ns * 16 + lm][ks * 32 + quad * 8];
      acc[ns] = __builtin_amdgcn_mfma_f32_16x16x32_f16(a, bf, acc[ns], 0, 0, 0);
    }
  }

  #pragma unroll
  for (int ns = 0; ns < 4; ++ns)
    #pragma unroll
    for (int r = 0; r < 4; ++r)
      os[wv * 16 + quad * 4 + r][ns * 16 + lm] = acc[ns][r];
  __syncthreads();

  const int o = tid >> 2, pq = (tid & 3) * 16;
  const float bias = bo[mt * 64 + o];
  float* dst = out + ((size_t)(b * CIN + mt * 64 + o)) * HW + p0 + pq;
  #pragma unroll
  for (int j = 0; j < 4; ++j) {
    float4 v = *(const float4*)&os[o][pq + j * 4];
    v.x += bias; v.y += bias; v.z += bias; v.w += bias;
    *(float4*)(dst + j * 4) = v;
  }
}

// ---------------------------------------------------------------------------
extern "C" void kernel_launch(void* const* d_in, const int* in_sizes, int n_in,
                              void* d_out, int out_size, void* d_ws, size_t ws_size,
                              hipStream_t stream)
{
  const float* x     = (const float*)d_in[0];   // [4,256,64,64]
  const float* w_qkv = (const float*)d_in[1];   // [384,256]
  const float* w_out = (const float*)d_in[2];   // [256,128]
  const float* b_out = (const float*)d_in[3];   // [256]
  float* out = (float*)d_out;

  char* ws = (char*)d_ws;
  _Float16* Qw  = (_Float16*)(ws);               //  4 MB [bh][p][d], log2e-scaled
  _Float16* Kw  = (_Float16*)(ws + (4u  << 20)); //  4 MB [bh][p][d]
  _Float16* Vtw = (_Float16*)(ws + (8u  << 20)); //  4 MB [bh][d][p]
  float*    Op  = (float*)   (ws + (12u << 20)); // 16 MB [2][4][4096][128] f32
  float*    lp  = (float*)   (ws + (28u << 20)); // 0.5MB [2][16][4096] f32

  dim3 blk(256);
  qkv_fused<<<dim3(6, 256), blk, 0, stream>>>(w_qkv, x, Qw, Kw, Vtw);
  attn<<<dim3(1024), blk, 0, stream>>>(Qw, Kw, Vtw, Op, lp);
  out_gemm<<<dim3(4, 256), blk, 0, stream>>>(w_out, Op, lp, b_out, out);
}

// Round 5
// 161.823 us; speedup vs baseline: 1.6344x; 1.6344x over previous
//
#include <hip/hip_runtime.h>
#include <hip/hip_fp16.h>

#define HEADS 4
#define DH    32
#define HW    4096
#define CIN   256
#define HID   128
#define KSPLIT 2
#define KHALF (HW / KSPLIT)
#define NIT   (KHALF / 64)

using half8    = __attribute__((ext_vector_type(8))) _Float16;
using half4    = __attribute__((ext_vector_type(4))) _Float16;
using half2v   = __attribute__((ext_vector_type(2))) _Float16;
using floatx4  = __attribute__((ext_vector_type(4))) float;
using floatx16 = __attribute__((ext_vector_type(16))) float;
using uint4v   = __attribute__((ext_vector_type(4))) unsigned;

// P = exp2(s_log2 - 3*log2e); log2(e) folded into Q pre-scale, shift folded
// into the S-MFMA C-initializer. Fixed shift (no running max) => split-K
// partials combine by pure addition.
#define SHIFT2 4.328085122666891f
#define WQSCALE 0.25508275947f   // 32^-0.5 * log2(e)

static __device__ __forceinline__ unsigned pkr(float a, float b) {
  return __builtin_bit_cast(unsigned, __builtin_amdgcn_cvt_pkrtz(a, b));
}

// ---------------------------------------------------------------------------
// qkv_fused: QKV[o][b,p] = (w_qkv f32->f16, Q rows pre-scaled) @ x^T.
// x transposed through fp32 t[64][65] LDS tile, K in 4 quarters of 64.
// grid (6 m-tiles, 256 n-tiles) x 256
// ---------------------------------------------------------------------------
__global__ __launch_bounds__(256) void qkv_fused(
    const float* __restrict__ w, const float* __restrict__ x,
    _Float16* __restrict__ Qw, _Float16* __restrict__ Kw,
    _Float16* __restrict__ Vtw)
{
  __shared__ float t[64][65];
  __shared__ _Float16 As[64][72];
  __shared__ _Float16 Bs[64][72];
  const int mt = blockIdx.x, nt = blockIdx.y;
  const int b = nt >> 6, p0 = (nt & 63) * 64;
  const int tid = threadIdx.x;
  const int wv = tid >> 6, lane = tid & 63, lm = lane & 15, quad = lane >> 4;
  const float wscale = (mt < 2) ? WQSCALE : 1.0f;

  const float* Ag = w + (size_t)(mt * 64) * CIN;
  const float* xb = x + (size_t)b * CIN * HW + p0;

  floatx4 acc[4] = {{0,0,0,0},{0,0,0,0},{0,0,0,0},{0,0,0,0}};

  for (int kq = 0; kq < 4; ++kq) {
    __syncthreads();
    #pragma unroll
    for (int i = 0; i < 4; ++i) {
      int ci = tid + i * 256;
      int cc = ci >> 4, p4 = (ci & 15) * 4;
      *(float4*)&t[cc][p4] =
          *(const float4*)(xb + (size_t)(kq * 64 + cc) * HW + p4);
    }
    #pragma unroll
    for (int i = 0; i < 2; ++i) {
      int ci = tid + i * 256;
      int r = ci >> 3, c8 = (ci & 7) * 8;
      const float* src = Ag + (size_t)r * CIN + kq * 64 + c8;
      float4 u0 = *(const float4*)(src);
      float4 u1 = *(const float4*)(src + 4);
      half8 h = {(_Float16)(u0.x * wscale), (_Float16)(u0.y * wscale),
                 (_Float16)(u0.z * wscale), (_Float16)(u0.w * wscale),
                 (_Float16)(u1.x * wscale), (_Float16)(u1.y * wscale),
                 (_Float16)(u1.z * wscale), (_Float16)(u1.w * wscale)};
      *(half8*)&As[r][c8] = h;
    }
    __syncthreads();
    #pragma unroll
    for (int i = 0; i < 2; ++i) {
      int idx = tid + i * 256;
      int p = idx >> 3, c0 = (idx & 7) * 8;
      half8 v;
      #pragma unroll
      for (int k = 0; k < 8; ++k) v[k] = (_Float16)t[c0 + k][p];
      *(half8*)&Bs[p][c0] = v;
    }
    __syncthreads();
    #pragma unroll
    for (int ks = 0; ks < 2; ++ks) {
      half8 a = *(const half8*)&As[wv * 16 + lm][ks * 32 + quad * 8];
      #pragma unroll
      for (int ns = 0; ns < 4; ++ns) {
        half8 bf = *(const half8*)&Bs[ns * 16 + lm][ks * 32 + quad * 8];
        acc[ns] = __builtin_amdgcn_mfma_f32_16x16x32_f16(a, bf, acc[ns], 0, 0, 0);
      }
    }
  }

  const int sec = mt >> 1;                    // 0=Q 1=K 2=V
  const int o_base = (mt & 1) * 64 + wv * 16 + quad * 4;
  const int hh = o_base >> 5, dd = o_base & 31;
  const int bh = b * HEADS + hh;
  if (sec < 2) {
    _Float16* dst = (sec == 0) ? Qw : Kw;
    #pragma unroll
    for (int ns = 0; ns < 4; ++ns) {
      int p = p0 + ns * 16 + lm;
      half4 v = {(_Float16)acc[ns][0], (_Float16)acc[ns][1],
                 (_Float16)acc[ns][2], (_Float16)acc[ns][3]};
      *(half4*)(dst + ((size_t)bh * HW + p) * DH + dd) = v;
    }
  } else {
    #pragma unroll
    for (int ns = 0; ns < 4; ++ns) {
      int p = p0 + ns * 16 + lm;
      #pragma unroll
      for (int r = 0; r < 4; ++r)
        Vtw[((size_t)bh * DH + dd + r) * HW + p] = (_Float16)acc[ns][r];
    }
  }
}

// ---------------------------------------------------------------------------
// attn: R3 LDS-staged structure (R4 proved direct-global gathers are 3x worse)
// rebuilt on 32x32x16 MFMAs: per 64-col iter, 4 S-MFMAs + 4 PV-MFMAs (was 32
// 16x16 MFMAs incl. 8 ones-MFMAs). Row sums are now lane-local f32 adds (the
// 32x32 C-layout gives each lane 16 k-rows of ONE q-column) + one final
// shfl_xor(32). P^T -> PV B-fragments built in-register via cvt_pkrtz +
// v_permlane32_swap_b32 (T12). ks/vt reads are 32-consecutive-row b128 ->
// would be 4-way bank conflicts; a 2-bit XOR swizzle on 16B slots (applied
// on write AND read, reg-staged) makes them ~conflict-free.
// grid (32 q-tiles, 16 bh, 2 k-halves) x 256; each wave owns 32 q-rows.
// ---------------------------------------------------------------------------
__global__ __launch_bounds__(256) void attn(
    const _Float16* __restrict__ Qw, const _Float16* __restrict__ Kw,
    const _Float16* __restrict__ Vtw, float* __restrict__ Op,
    float* __restrict__ lp)
{
  __shared__ _Float16 ks[2][64][40];          // [phase][k][d]  10.0 KB
  __shared__ _Float16 vt[2][32][72];          // [phase][d][k]   9.0 KB

  const int bh = blockIdx.y, qt = blockIdx.x, z = blockIdx.z;
  const int tid = threadIdx.x;
  const int wv = tid >> 6, lane = tid & 63;
  const int l31 = lane & 31, hi = lane >> 5;

  // Q fragments: B-operand of 32x32x16 = col q = l31, k-rows (hi)*8.. per dblk
  const _Float16* qbase =
      Qw + ((size_t)bh * HW + qt * 128 + wv * 32 + l31) * DH + hi * 8;
  const half8 qb0 = *(const half8*)qbase;        // d = hi*8 + 0..7
  const half8 qb1 = *(const half8*)(qbase + 16); // d = 16 + hi*8 + 0..7

  const floatx16 shift16 = {-SHIFT2,-SHIFT2,-SHIFT2,-SHIFT2,
                            -SHIFT2,-SHIFT2,-SHIFT2,-SHIFT2,
                            -SHIFT2,-SHIFT2,-SHIFT2,-SHIFT2,
                            -SHIFT2,-SHIFT2,-SHIFT2,-SHIFT2};
  floatx16 oT = {0,0,0,0,0,0,0,0,0,0,0,0,0,0,0,0};
  float lsum = 0.0f;

  // this block's K-range: [z*KHALF, z*KHALF + KHALF)
  const _Float16* kbase = Kw  + (size_t)bh * HW * DH + (size_t)z * KHALF * DH;
  const _Float16* vbase = Vtw + (size_t)bh * DH * HW + (size_t)z * KHALF;
  const int kr = tid >> 2, kc = (tid & 3) * 8;
  const int vr = tid >> 3, vc = (tid & 7) * 8;
  // swizzled LDS write columns (16B-slot XOR with row-octet key)
  const int kwc = (((tid & 3) ^ ((kr >> 3) & 3)) << 3);
  const int vwc = (((tid & 7) ^ ((vr >> 3) & 3)) << 3);
  // read-side XOR key (row = l31 [+t*32, key unchanged])
  const int kx = (l31 >> 3) & 3;

  // prologue: stage K-step 0, prefetch K-step 1
  half8 kA = *(const half8*)(kbase + (size_t)kr * DH + kc);
  half8 vA = *(const half8*)(vbase + (size_t)vr * HW + vc);
  *(half8*)&ks[0][kr][kwc] = kA;
  *(half8*)&vt[0][vr][vwc] = vA;
  kA = *(const half8*)(kbase + ((size_t)64 + kr) * DH + kc);
  vA = *(const half8*)(vbase + (size_t)vr * HW + 64 + vc);
  __syncthreads();

  for (int it = 0; it < NIT; ++it) {
    const int ph = it & 1, nx = ph ^ 1;

    // ---- hoisted swizzled LDS reads, consumption order ----
    half8 ka[2][2];   // [t(k-32-group)][dblk]
    half8 va[4];      // [16-k tile]
    #pragma unroll
    for (int t = 0; t < 2; ++t)
      #pragma unroll
      for (int d = 0; d < 2; ++d)
        ka[t][d] = *(const half8*)&ks[ph][t * 32 + l31][((d * 2 + hi) ^ kx) << 3];
    #pragma unroll
    for (int k4 = 0; k4 < 4; ++k4)
      va[k4] = *(const half8*)&vt[ph][l31][((k4 * 2 + hi) ^ kx) << 3];

    // ---- stage next K-step, then prefetch K-step it+2 ----
    *(half8*)&ks[nx][kr][kwc] = kA;
    *(half8*)&vt[nx][vr][vwc] = vA;
    size_t koff = (size_t)(it + 2) * 64;
    if (koff > KHALF - 64) koff = KHALF - 64;
    kA = *(const half8*)(kbase + (koff + kr) * DH + kc);
    vA = *(const half8*)(vbase + (size_t)vr * HW + koff + vc);

    // ---- compute: per 32-k group, 2 S-MFMA -> 16 exp -> pack -> 2 PV-MFMA --
    #pragma unroll
    for (int t = 0; t < 2; ++t) {
      floatx16 sT = __builtin_amdgcn_mfma_f32_32x32x16_f16(ka[t][0], qb0, shift16, 0, 0, 0);
      sT = __builtin_amdgcn_mfma_f32_32x32x16_f16(ka[t][1], qb1, sT, 0, 0, 0);
      float e[16];
      #pragma unroll
      for (int r = 0; r < 16; ++r) e[r] = __builtin_amdgcn_exp2f(sT[r]);
      lsum += (((e[0]+e[1])+(e[2]+e[3]))+((e[4]+e[5])+(e[6]+e[7])))
            + (((e[8]+e[9])+(e[10]+e[11]))+((e[12]+e[13])+(e[14]+e[15])));
      // P^T B-fragments: lane needs k-rows (hi)*8..+8 of each 16-k tile;
      // lane holds k = (r&3)+8*(r>>2)+4*hi -> cvt_pk pairs + permlane32_swap.
      unsigned w0 = pkr(e[0],  e[1]),  w1 = pkr(e[2],  e[3]);
      unsigned w2 = pkr(e[4],  e[5]),  w3 = pkr(e[6],  e[7]);
      unsigned w4 = pkr(e[8],  e[9]),  w5 = pkr(e[10], e[11]);
      unsigned w6 = pkr(e[12], e[13]), w7 = pkr(e[14], e[15]);
      asm("v_permlane32_swap_b32 %0, %1" : "+v"(w0), "+v"(w2));
      asm("v_permlane32_swap_b32 %0, %1" : "+v"(w1), "+v"(w3));
      asm("v_permlane32_swap_b32 %0, %1" : "+v"(w4), "+v"(w6));
      asm("v_permlane32_swap_b32 %0, %1" : "+v"(w5), "+v"(w7));
      uint4v lo4 = {w0, w1, w2, w3}, hi4 = {w4, w5, w6, w7};
      half8 pbLo = __builtin_bit_cast(half8, lo4);
      half8 pbHi = __builtin_bit_cast(half8, hi4);
      oT = __builtin_amdgcn_mfma_f32_32x32x16_f16(va[2*t],     pbLo, oT, 0, 0, 0);
      oT = __builtin_amdgcn_mfma_f32_32x32x16_f16(va[2*t + 1], pbHi, oT, 0, 0, 0);
    }
    __syncthreads();
  }

  // epilogue: full row-sum via one cross-half exchange; unnormalized f32
  // O^T partials -> Op[z][b][row][hid]; row-sum partials -> lp[z][bh][row].
  lsum += __shfl_xor(lsum, 32, 64);
  const int b = bh >> 2, hh = bh & 3;
  const int row = qt * 128 + wv * 32 + l31;
  float* obase = Op + ((size_t)z * 4 * HW + (size_t)b * HW + row) * HID + hh * DH;
  #pragma unroll
  for (int r0 = 0; r0 < 4; ++r0) {
    float4 v = {oT[4*r0], oT[4*r0+1], oT[4*r0+2], oT[4*r0+3]};
    *(float4*)(obase + 8 * r0 + 4 * hi) = v;   // d = 8*r0 + 4*hi + 0..3
  }
  if (lane < 32)
    lp[(size_t)z * HEADS * 4 * HW + (size_t)bh * HW + row] = lsum;
}

// ---------------------------------------------------------------------------
// out_gemm: out[o][b,p] = w_out(256x128, cvt inline) @ Ot^T + bias.
// Split-K combine folded into B-staging — reads the two f32 O-partials,
// adds, normalizes by 1/(l0+l1) (per row & head), cvt to f16.
// Tile 64x64, K=128. grid (4 m-tiles, 256 n-tiles) x 256.
// ---------------------------------------------------------------------------
__global__ __launch_bounds__(256) void out_gemm(
    const float* __restrict__ wo, const float* __restrict__ Op,
    const float* __restrict__ lp, const float* __restrict__ bo,
    float* __restrict__ out)
{
  __shared__ _Float16 As[64][136];
  __shared__ _Float16 Bs[64][136];
  __shared__ float os[64][68];
  __shared__ float inv_l[64][4];
  const int mt = blockIdx.x, nt = blockIdx.y;
  const int b = nt >> 6, p0 = (nt & 63) * 64;
  const int tid = threadIdx.x;
  const int wv = tid >> 6, lane = tid & 63, lm = lane & 15, quad = lane >> 4;

  // combine row sums: inv_l[p][head] = 1/(l_z0 + l_z1)
  {
    const int p = tid >> 2, hh = tid & 3;
    const size_t qi = (size_t)(b * HEADS + hh) * HW + p0 + p;
    inv_l[p][hh] = 1.0f / (lp[qi] + lp[(size_t)HEADS * 4 * HW + qi]);
  }
  __syncthreads();

  const float* Ag  = wo + (size_t)(mt * 64) * HID;
  const float* Bp0 = Op + ((size_t)b * HW + p0) * HID;          // z = 0
  const float* Bp1 = Bp0 + (size_t)4 * HW * HID;                // z = 1

  #pragma unroll
  for (int i = 0; i < 4; ++i) {
    int ci = tid + i * 256;
    int r = ci >> 4, c8 = (ci & 15) * 8;
    const float* src = Ag + (size_t)r * HID + c8;
    float4 u0 = *(const float4*)(src);
    float4 u1 = *(const float4*)(src + 4);
    half8 h = {(_Float16)u0.x, (_Float16)u0.y, (_Float16)u0.z, (_Float16)u0.w,
               (_Float16)u1.x, (_Float16)u1.y, (_Float16)u1.z, (_Float16)u1.w};
    *(half8*)&As[r][c8] = h;

    const float* s0 = Bp0 + (size_t)r * HID + c8;
    const float* s1 = Bp1 + (size_t)r * HID + c8;
    float4 o0 = *(const float4*)(s0);
    float4 o1 = *(const float4*)(s0 + 4);
    float4 o2 = *(const float4*)(s1);
    float4 o3 = *(const float4*)(s1 + 4);
    const float sc = inv_l[r][c8 >> 5];   // 8 cols stay within one head
    half8 hb = {(_Float16)((o0.x + o2.x) * sc), (_Float16)((o0.y + o2.y) * sc),
                (_Float16)((o0.z + o2.z) * sc), (_Float16)((o0.w + o2.w) * sc),
                (_Float16)((o1.x + o3.x) * sc), (_Float16)((o1.y + o3.y) * sc),
                (_Float16)((o1.z + o3.z) * sc), (_Float16)((o1.w + o3.w) * sc)};
    *(half8*)&Bs[r][c8] = hb;
  }
  __syncthreads();

  floatx4 acc[4] = {{0,0,0,0},{0,0,0,0},{0,0,0,0},{0,0,0,0}};
  #pragma unroll
  for (int ks = 0; ks < 4; ++ks) {
    half8 a = *(const half8*)&As[wv * 16 + lm][ks * 32 + quad * 8];
    #pragma unroll
    for (int ns = 0; ns < 4; ++ns) {
      half8 bf = *(const half8*)&Bs[ns * 16 + lm][ks * 32 + quad * 8];
      acc[ns] = __builtin_amdgcn_mfma_f32_16x16x32_f16(a, bf, acc[ns], 0, 0, 0);
    }
  }

  #pragma unroll
  for (int ns = 0; ns < 4; ++ns)
    #pragma unroll
    for (int r = 0; r < 4; ++r)
      os[wv * 16 + quad * 4 + r][ns * 16 + lm] = acc[ns][r];
  __syncthreads();

  const int o = tid >> 2, pq = (tid & 3) * 16;
  const float bias = bo[mt * 64 + o];
  float* dst = out + ((size_t)(b * CIN + mt * 64 + o)) * HW + p0 + pq;
  #pragma unroll
  for (int j = 0; j < 4; ++j) {
    float4 v = *(const float4*)&os[o][pq + j * 4];
    v.x += bias; v.y += bias; v.z += bias; v.w += bias;
    *(float4*)(dst + j * 4) = v;
  }
}

// ---------------------------------------------------------------------------
extern "C" void kernel_launch(void* const* d_in, const int* in_sizes, int n_in,
                              void* d_out, int out_size, void* d_ws, size_t ws_size,
                              hipStream_t stream)
{
  const float* x     = (const float*)d_in[0];   // [4,256,64,64]
  const float* w_qkv = (const float*)d_in[1];   // [384,256]
  const float* w_out = (const float*)d_in[2];   // [256,128]
  const float* b_out = (const float*)d_in[3];   // [256]
  float* out = (float*)d_out;

  char* ws = (char*)d_ws;
  _Float16* Qw  = (_Float16*)(ws);               //  4 MB [bh][p][d], log2e-scaled
  _Float16* Kw  = (_Float16*)(ws + (4u  << 20)); //  4 MB [bh][p][d]
  _Float16* Vtw = (_Float16*)(ws + (8u  << 20)); //  4 MB [bh][d][p]
  float*    Op  = (float*)   (ws + (12u << 20)); // 16 MB [2][4][4096][128] f32
  float*    lp  = (float*)   (ws + (28u << 20)); // 0.5MB [2][16][4096] f32

  dim3 blk(256);
  qkv_fused<<<dim3(6, 256), blk, 0, stream>>>(w_qkv, x, Qw, Kw, Vtw);
  attn<<<dim3(32, 16, KSPLIT), blk, 0, stream>>>(Qw, Kw, Vtw, Op, lp);
  out_gemm<<<dim3(4, 256), blk, 0, stream>>>(w_out, Op, lp, b_out, out);
}

// Round 6
// 157.326 us; speedup vs baseline: 1.6811x; 1.0286x over previous
//
#include <hip/hip_runtime.h>
#include <hip/hip_fp16.h>

#define HEADS 4
#define DH    32
#define HW    4096
#define CIN   256
#define HID   128
#define KSPLIT 2
#define KHALF (HW / KSPLIT)
#define NIT   (KHALF / 64)

using half8    = __attribute__((ext_vector_type(8))) _Float16;
using half4    = __attribute__((ext_vector_type(4))) _Float16;
using half2v   = __attribute__((ext_vector_type(2))) _Float16;
using floatx4  = __attribute__((ext_vector_type(4))) float;
using floatx16 = __attribute__((ext_vector_type(16))) float;
using uint4v   = __attribute__((ext_vector_type(4))) unsigned;

// P = exp2(s_log2 - 3*log2e); log2(e) folded into Q pre-scale, shift folded
// into the S-MFMA C-initializer. Fixed shift (no running max) => split-K
// partials combine by pure addition.
#define SHIFT2 4.328085122666891f
#define WQSCALE 0.25508275947f   // 32^-0.5 * log2(e)

static __device__ __forceinline__ unsigned pkr(float a, float b) {
  return __builtin_bit_cast(unsigned, __builtin_amdgcn_cvt_pkrtz(a, b));
}

// ---------------------------------------------------------------------------
// qkv_fused v2: THIS ROUND — m-tile merge. Old grid (6,256) re-read x once
// per m-tile: 96 MB HBM. w_qkv (393 KB) is L2-resident, so re-reading W is
// ~free while re-reading x is not. New grid (2,256): each block computes 3
// m-tiles (192 out-channels) for its 64 pixels; x read 2x = 32 MB (-64 MB).
// x transposed through fp32 t[64][65] LDS once per kq, shared by all 3 mt.
// LDS 35 KB -> 2 blocks/CU = 8 waves/CU.
// ---------------------------------------------------------------------------
__global__ __launch_bounds__(256) void qkv_fused(
    const float* __restrict__ w, const float* __restrict__ x,
    _Float16* __restrict__ Qw, _Float16* __restrict__ Kw,
    _Float16* __restrict__ Vtw)
{
  __shared__ float t[64][65];
  __shared__ _Float16 As[64][72];
  __shared__ _Float16 Bs[64][72];
  const int mg = blockIdx.x, nt = blockIdx.y;
  const int b = nt >> 6, p0 = (nt & 63) * 64;
  const int tid = threadIdx.x;
  const int wv = tid >> 6, lane = tid & 63, lm = lane & 15, quad = lane >> 4;

  const float* xb = x + (size_t)b * CIN * HW + p0;

  floatx4 acc[3][4] = {{{0,0,0,0},{0,0,0,0},{0,0,0,0},{0,0,0,0}},
                       {{0,0,0,0},{0,0,0,0},{0,0,0,0},{0,0,0,0}},
                       {{0,0,0,0},{0,0,0,0},{0,0,0,0},{0,0,0,0}}};

  for (int kq = 0; kq < 4; ++kq) {
    __syncthreads();   // t & Bs free (prev kq consumers done)
    #pragma unroll
    for (int i = 0; i < 4; ++i) {
      int ci = tid + i * 256;
      int cc = ci >> 4, p4 = (ci & 15) * 4;
      *(float4*)&t[cc][p4] =
          *(const float4*)(xb + (size_t)(kq * 64 + cc) * HW + p4);
    }
    __syncthreads();   // t ready
    #pragma unroll
    for (int i = 0; i < 2; ++i) {
      int idx = tid + i * 256;
      int p = idx >> 3, c0 = (idx & 7) * 8;
      half8 v;
      #pragma unroll
      for (int k = 0; k < 8; ++k) v[k] = (_Float16)t[c0 + k][p];
      *(half8*)&Bs[p][c0] = v;
    }

    #pragma unroll
    for (int im = 0; im < 3; ++im) {
      const int mt = mg * 3 + im;
      const float wscale = (mt < 2) ? WQSCALE : 1.0f;
      const float* Ag = w + (size_t)(mt * 64) * CIN;
      __syncthreads();   // Bs ready (im=0) / As free (im>0)
      #pragma unroll
      for (int i = 0; i < 2; ++i) {
        int ci = tid + i * 256;
        int r = ci >> 3, c8 = (ci & 7) * 8;
        const float* src = Ag + (size_t)r * CIN + kq * 64 + c8;
        float4 u0 = *(const float4*)(src);
        float4 u1 = *(const float4*)(src + 4);
        half8 h = {(_Float16)(u0.x * wscale), (_Float16)(u0.y * wscale),
                   (_Float16)(u0.z * wscale), (_Float16)(u0.w * wscale),
                   (_Float16)(u1.x * wscale), (_Float16)(u1.y * wscale),
                   (_Float16)(u1.z * wscale), (_Float16)(u1.w * wscale)};
        *(half8*)&As[r][c8] = h;
      }
      __syncthreads();   // As ready
      #pragma unroll
      for (int ks = 0; ks < 2; ++ks) {
        half8 a = *(const half8*)&As[wv * 16 + lm][ks * 32 + quad * 8];
        #pragma unroll
        for (int ns = 0; ns < 4; ++ns) {
          half8 bf = *(const half8*)&Bs[ns * 16 + lm][ks * 32 + quad * 8];
          acc[im][ns] = __builtin_amdgcn_mfma_f32_16x16x32_f16(a, bf, acc[im][ns], 0, 0, 0);
        }
      }
    }
  }

  #pragma unroll
  for (int im = 0; im < 3; ++im) {
    const int mt = mg * 3 + im;
    const int sec = mt >> 1;                    // 0=Q 1=K 2=V
    const int o_base = (mt & 1) * 64 + wv * 16 + quad * 4;
    const int hh = o_base >> 5, dd = o_base & 31;
    const int bh = b * HEADS + hh;
    if (sec < 2) {
      _Float16* dst = (sec == 0) ? Qw : Kw;
      #pragma unroll
      for (int ns = 0; ns < 4; ++ns) {
        int p = p0 + ns * 16 + lm;
        half4 v = {(_Float16)acc[im][ns][0], (_Float16)acc[im][ns][1],
                   (_Float16)acc[im][ns][2], (_Float16)acc[im][ns][3]};
        *(half4*)(dst + ((size_t)bh * HW + p) * DH + dd) = v;
      }
    } else {
      #pragma unroll
      for (int ns = 0; ns < 4; ++ns) {
        int p = p0 + ns * 16 + lm;
        #pragma unroll
        for (int r = 0; r < 4; ++r)
          Vtw[((size_t)bh * DH + dd + r) * HW + p] = (_Float16)acc[im][ns][r];
      }
    }
  }
}

// ---------------------------------------------------------------------------
// attn: unchanged from R5 (32x32x16 MFMA dataflow, split-K x2, LDS-staged).
// Known remaining lever: 9.47M bank-conflict cycles (~15 us) — next round.
// ---------------------------------------------------------------------------
__global__ __launch_bounds__(256) void attn(
    const _Float16* __restrict__ Qw, const _Float16* __restrict__ Kw,
    const _Float16* __restrict__ Vtw, float* __restrict__ Op,
    float* __restrict__ lp)
{
  __shared__ _Float16 ks[2][64][40];          // [phase][k][d]  10.0 KB
  __shared__ _Float16 vt[2][32][72];          // [phase][d][k]   9.0 KB

  const int bh = blockIdx.y, qt = blockIdx.x, z = blockIdx.z;
  const int tid = threadIdx.x;
  const int wv = tid >> 6, lane = tid & 63;
  const int l31 = lane & 31, hi = lane >> 5;

  const _Float16* qbase =
      Qw + ((size_t)bh * HW + qt * 128 + wv * 32 + l31) * DH + hi * 8;
  const half8 qb0 = *(const half8*)qbase;        // d = hi*8 + 0..7
  const half8 qb1 = *(const half8*)(qbase + 16); // d = 16 + hi*8 + 0..7

  const floatx16 shift16 = {-SHIFT2,-SHIFT2,-SHIFT2,-SHIFT2,
                            -SHIFT2,-SHIFT2,-SHIFT2,-SHIFT2,
                            -SHIFT2,-SHIFT2,-SHIFT2,-SHIFT2,
                            -SHIFT2,-SHIFT2,-SHIFT2,-SHIFT2};
  floatx16 oT = {0,0,0,0,0,0,0,0,0,0,0,0,0,0,0,0};
  float lsum = 0.0f;

  const _Float16* kbase = Kw  + (size_t)bh * HW * DH + (size_t)z * KHALF * DH;
  const _Float16* vbase = Vtw + (size_t)bh * DH * HW + (size_t)z * KHALF;
  const int kr = tid >> 2, kc = (tid & 3) * 8;
  const int vr = tid >> 3, vc = (tid & 7) * 8;
  const int kwc = (((tid & 3) ^ ((kr >> 3) & 3)) << 3);
  const int vwc = (((tid & 7) ^ ((vr >> 3) & 3)) << 3);
  const int kx = (l31 >> 3) & 3;

  half8 kA = *(const half8*)(kbase + (size_t)kr * DH + kc);
  half8 vA = *(const half8*)(vbase + (size_t)vr * HW + vc);
  *(half8*)&ks[0][kr][kwc] = kA;
  *(half8*)&vt[0][vr][vwc] = vA;
  kA = *(const half8*)(kbase + ((size_t)64 + kr) * DH + kc);
  vA = *(const half8*)(vbase + (size_t)vr * HW + 64 + vc);
  __syncthreads();

  for (int it = 0; it < NIT; ++it) {
    const int ph = it & 1, nx = ph ^ 1;

    half8 ka[2][2];
    half8 va[4];
    #pragma unroll
    for (int t = 0; t < 2; ++t)
      #pragma unroll
      for (int d = 0; d < 2; ++d)
        ka[t][d] = *(const half8*)&ks[ph][t * 32 + l31][((d * 2 + hi) ^ kx) << 3];
    #pragma unroll
    for (int k4 = 0; k4 < 4; ++k4)
      va[k4] = *(const half8*)&vt[ph][l31][((k4 * 2 + hi) ^ kx) << 3];

    *(half8*)&ks[nx][kr][kwc] = kA;
    *(half8*)&vt[nx][vr][vwc] = vA;
    size_t koff = (size_t)(it + 2) * 64;
    if (koff > KHALF - 64) koff = KHALF - 64;
    kA = *(const half8*)(kbase + (koff + kr) * DH + kc);
    vA = *(const half8*)(vbase + (size_t)vr * HW + koff + vc);

    #pragma unroll
    for (int t = 0; t < 2; ++t) {
      floatx16 sT = __builtin_amdgcn_mfma_f32_32x32x16_f16(ka[t][0], qb0, shift16, 0, 0, 0);
      sT = __builtin_amdgcn_mfma_f32_32x32x16_f16(ka[t][1], qb1, sT, 0, 0, 0);
      float e[16];
      #pragma unroll
      for (int r = 0; r < 16; ++r) e[r] = __builtin_amdgcn_exp2f(sT[r]);
      lsum += (((e[0]+e[1])+(e[2]+e[3]))+((e[4]+e[5])+(e[6]+e[7])))
            + (((e[8]+e[9])+(e[10]+e[11]))+((e[12]+e[13])+(e[14]+e[15])));
      unsigned w0 = pkr(e[0],  e[1]),  w1 = pkr(e[2],  e[3]);
      unsigned w2 = pkr(e[4],  e[5]),  w3 = pkr(e[6],  e[7]);
      unsigned w4 = pkr(e[8],  e[9]),  w5 = pkr(e[10], e[11]);
      unsigned w6 = pkr(e[12], e[13]), w7 = pkr(e[14], e[15]);
      asm("v_permlane32_swap_b32 %0, %1" : "+v"(w0), "+v"(w2));
      asm("v_permlane32_swap_b32 %0, %1" : "+v"(w1), "+v"(w3));
      asm("v_permlane32_swap_b32 %0, %1" : "+v"(w4), "+v"(w6));
      asm("v_permlane32_swap_b32 %0, %1" : "+v"(w5), "+v"(w7));
      uint4v lo4 = {w0, w1, w2, w3}, hi4 = {w4, w5, w6, w7};
      half8 pbLo = __builtin_bit_cast(half8, lo4);
      half8 pbHi = __builtin_bit_cast(half8, hi4);
      oT = __builtin_amdgcn_mfma_f32_32x32x16_f16(va[2*t],     pbLo, oT, 0, 0, 0);
      oT = __builtin_amdgcn_mfma_f32_32x32x16_f16(va[2*t + 1], pbHi, oT, 0, 0, 0);
    }
    __syncthreads();
  }

  lsum += __shfl_xor(lsum, 32, 64);
  const int b = bh >> 2, hh = bh & 3;
  const int row = qt * 128 + wv * 32 + l31;
  float* obase = Op + ((size_t)z * 4 * HW + (size_t)b * HW + row) * HID + hh * DH;
  #pragma unroll
  for (int r0 = 0; r0 < 4; ++r0) {
    float4 v = {oT[4*r0], oT[4*r0+1], oT[4*r0+2], oT[4*r0+3]};
    *(float4*)(obase + 8 * r0 + 4 * hi) = v;
  }
  if (lane < 32)
    lp[(size_t)z * HEADS * 4 * HW + (size_t)bh * HW + row] = lsum;
}

// ---------------------------------------------------------------------------
// out_gemm v2: THIS ROUND — m-tile merge. Old grid (4,256) re-read the f32
// O-partials once per m-tile: 67 MB. w_out (128 KB) is L2-resident. New grid
// (2,256): each block stages the combined+normalized B tile ONCE, then loops
// 2 m-tiles re-staging only As from w_out. Op read 2x = 33.6 MB (-34 MB).
// os-staging dropped (direct f32 stores, 64B segments) to keep LDS at 36 KB
// -> 2 blocks/CU.
// ---------------------------------------------------------------------------
__global__ __launch_bounds__(256) void out_gemm(
    const float* __restrict__ wo, const float* __restrict__ Op,
    const float* __restrict__ lp, const float* __restrict__ bo,
    float* __restrict__ out)
{
  __shared__ _Float16 As[64][136];
  __shared__ _Float16 Bs[64][136];
  __shared__ float inv_l[64][4];
  const int mg = blockIdx.x, nt = blockIdx.y;
  const int b = nt >> 6, p0 = (nt & 63) * 64;
  const int tid = threadIdx.x;
  const int wv = tid >> 6, lane = tid & 63, lm = lane & 15, quad = lane >> 4;

  // combine row sums: inv_l[p][head] = 1/(l_z0 + l_z1)
  {
    const int p = tid >> 2, hh = tid & 3;
    const size_t qi = (size_t)(b * HEADS + hh) * HW + p0 + p;
    inv_l[p][hh] = 1.0f / (lp[qi] + lp[(size_t)HEADS * 4 * HW + qi]);
  }
  __syncthreads();

  const float* Bp0 = Op + ((size_t)b * HW + p0) * HID;          // z = 0
  const float* Bp1 = Bp0 + (size_t)4 * HW * HID;                // z = 1

  // stage combined B tile once
  #pragma unroll
  for (int i = 0; i < 4; ++i) {
    int ci = tid + i * 256;
    int r = ci >> 4, c8 = (ci & 15) * 8;
    const float* s0 = Bp0 + (size_t)r * HID + c8;
    const float* s1 = Bp1 + (size_t)r * HID + c8;
    float4 o0 = *(const float4*)(s0);
    float4 o1 = *(const float4*)(s0 + 4);
    float4 o2 = *(const float4*)(s1);
    float4 o3 = *(const float4*)(s1 + 4);
    const float sc = inv_l[r][c8 >> 5];   // 8 cols stay within one head
    half8 hb = {(_Float16)((o0.x + o2.x) * sc), (_Float16)((o0.y + o2.y) * sc),
                (_Float16)((o0.z + o2.z) * sc), (_Float16)((o0.w + o2.w) * sc),
                (_Float16)((o1.x + o3.x) * sc), (_Float16)((o1.y + o3.y) * sc),
                (_Float16)((o1.z + o3.z) * sc), (_Float16)((o1.w + o3.w) * sc)};
    *(half8*)&Bs[r][c8] = hb;
  }

  #pragma unroll
  for (int im = 0; im < 2; ++im) {
    const int mt = mg * 2 + im;
    const float* Ag = wo + (size_t)(mt * 64) * HID;
    __syncthreads();   // Bs ready (im=0) / As free (im=1)
    #pragma unroll
    for (int i = 0; i < 4; ++i) {
      int ci = tid + i * 256;
      int r = ci >> 4, c8 = (ci & 15) * 8;
      const float* src = Ag + (size_t)r * HID + c8;
      float4 u0 = *(const float4*)(src);
      float4 u1 = *(const float4*)(src + 4);
      half8 h = {(_Float16)u0.x, (_Float16)u0.y, (_Float16)u0.z, (_Float16)u0.w,
                 (_Float16)u1.x, (_Float16)u1.y, (_Float16)u1.z, (_Float16)u1.w};
      *(half8*)&As[r][c8] = h;
    }
    __syncthreads();   // As ready

    floatx4 acc[4] = {{0,0,0,0},{0,0,0,0},{0,0,0,0},{0,0,0,0}};
    #pragma unroll
    for (int ks = 0; ks < 4; ++ks) {
      half8 a = *(const half8*)&As[wv * 16 + lm][ks * 32 + quad * 8];
      #pragma unroll
      for (int ns = 0; ns < 4; ++ns) {
        half8 bf = *(const half8*)&Bs[ns * 16 + lm][ks * 32 + quad * 8];
        acc[ns] = __builtin_amdgcn_mfma_f32_16x16x32_f16(a, bf, acc[ns], 0, 0, 0);
      }
    }

    // direct stores: C[o][p], o = mt*64 + wv*16 + quad*4 + r, p = p0 + ns*16 + lm
    const int o_loc = wv * 16 + quad * 4;
    #pragma unroll
    for (int r = 0; r < 4; ++r) {
      const int o = mt * 64 + o_loc + r;
      const float bias = bo[o];
      float* dst = out + ((size_t)(b * CIN + o)) * HW + p0 + lm;
      #pragma unroll
      for (int ns = 0; ns < 4; ++ns)
        dst[ns * 16] = acc[ns][r] + bias;
    }
  }
}

// ---------------------------------------------------------------------------
extern "C" void kernel_launch(void* const* d_in, const int* in_sizes, int n_in,
                              void* d_out, int out_size, void* d_ws, size_t ws_size,
                              hipStream_t stream)
{
  const float* x     = (const float*)d_in[0];   // [4,256,64,64]
  const float* w_qkv = (const float*)d_in[1];   // [384,256]
  const float* w_out = (const float*)d_in[2];   // [256,128]
  const float* b_out = (const float*)d_in[3];   // [256]
  float* out = (float*)d_out;

  char* ws = (char*)d_ws;
  _Float16* Qw  = (_Float16*)(ws);               //  4 MB [bh][p][d], log2e-scaled
  _Float16* Kw  = (_Float16*)(ws + (4u  << 20)); //  4 MB [bh][p][d]
  _Float16* Vtw = (_Float16*)(ws + (8u  << 20)); //  4 MB [bh][d][p]
  float*    Op  = (float*)   (ws + (12u << 20)); // 16 MB [2][4][4096][128] f32
  float*    lp  = (float*)   (ws + (28u << 20)); // 0.5MB [2][16][4096] f32

  dim3 blk(256);
  qkv_fused<<<dim3(2, 256), blk, 0, stream>>>(w_qkv, x, Qw, Kw, Vtw);
  attn<<<dim3(32, 16, KSPLIT), blk, 0, stream>>>(Qw, Kw, Vtw, Op, lp);
  out_gemm<<<dim3(2, 256), blk, 0, stream>>>(w_out, Op, lp, b_out, out);
}